// Round 6
// baseline (101.969 us; speedup 1.0000x reference)
//
#include <hip/hip_runtime.h>

// frames: [N=16, B=4, C=64, H=128, W=128] fp32
// out[i] = frames[i]^2 * sum_j frames[j]
//
// Half-wave frame split: lanes 0-31 own frames 0-7, lanes 32-63 own frames
// 8-15, both halves covering the SAME 32 f32x4 elements. Each lane does
// 8 x 16B nt-loads (32 data VGPRs -> still 8 waves/SIMD), partial sum,
// then a 4x __shfl_xor(32) to combine the two half-sums, 8 x 16B stores.
// Gets dwordx4 access width AND full occupancy at once.

typedef float f32x4 __attribute__((ext_vector_type(4)));

constexpr int N_FRAMES = 16;
constexpr int M_ELEMS  = 4 * 64 * 128 * 128;   // 4,194,304 fp32 per frame
constexpr int M4       = M_ELEMS / 4;          // 1,048,576 f32x4 per frame

__global__ __launch_bounds__(256, 8) void frame_similarly_kernel(
    const f32x4* __restrict__ in, f32x4* __restrict__ out) {
    const int lane = threadIdx.x & 63;
    const int sub  = lane & 31;            // element slot within half-wave
    const int f0   = (lane >> 5) * 8;      // frame base: 0 or 8
    const int wave = (blockIdx.x * blockDim.x + threadIdx.x) >> 6;
    const size_t e4 = (size_t)wave * 32 + sub;   // grid exactly covers M4

    f32x4 v[8];
    #pragma unroll
    for (int i = 0; i < 8; ++i) {
        v[i] = __builtin_nontemporal_load(&in[(size_t)(f0 + i) * M4 + e4]);
    }

    f32x4 s = v[0];
    #pragma unroll
    for (int i = 1; i < 8; ++i) s += v[i];

    // combine half-wave partial sums (lane ^ 32 holds the other 8 frames)
    f32x4 so;
    so.x = __shfl_xor(s.x, 32, 64);
    so.y = __shfl_xor(s.y, 32, 64);
    so.z = __shfl_xor(s.z, 32, 64);
    so.w = __shfl_xor(s.w, 32, 64);
    s += so;

    #pragma unroll
    for (int i = 0; i < 8; ++i) {
        f32x4 o = v[i] * v[i] * s;
        out[(size_t)(f0 + i) * M4 + e4] = o;   // regular write-back store
    }
}

extern "C" void kernel_launch(void* const* d_in, const int* in_sizes, int n_in,
                              void* d_out, int out_size, void* d_ws, size_t ws_size,
                              hipStream_t stream) {
    const f32x4* in  = (const f32x4*)d_in[0];
    f32x4*       out = (f32x4*)d_out;

    const int threads = 256;
    // each wave covers 32 f32x4 elements; 4 waves/block -> 128 per block
    const int blocks  = M4 / 128;   // 8192, exact
    frame_similarly_kernel<<<blocks, threads, 0, stream>>>(in, out);
}

// Round 8
// 99.965 us; speedup vs baseline: 1.0200x; 1.0200x over previous
//
#include <hip/hip_runtime.h>

// frames: [N=16, B=4, C=64, H=128, W=128] fp32
// out[i] = frames[i]^2 * sum_j frames[j]
//
// Half-wave frame split (as R6): lanes 0-31 own frames 0-7, lanes 32-63 own
// frames 8-15, both halves covering the SAME 32 f32x4 elements. 8 x 16B
// nt-loads per lane (32 data VGPRs -> 8 waves/SIMD), partial sum, then the
// two half-wave partials are combined with __builtin_amdgcn_permlane32_swap
// (pure-VALU lane^32 exchange; the BUILTIN, so the compiler handles the
// permlane read-after-VALU-write hazard that broke R7's inline asm).
// 8 x 16B write-back stores.

typedef float    f32x4 __attribute__((ext_vector_type(4)));
typedef unsigned u32x2 __attribute__((ext_vector_type(2)));

constexpr int N_FRAMES = 16;
constexpr int M_ELEMS  = 4 * 64 * 128 * 128;   // 4,194,304 fp32 per frame
constexpr int M4       = M_ELEMS / 4;          // 1,048,576 f32x4 per frame

__global__ __launch_bounds__(256, 8) void frame_similarly_kernel(
    const f32x4* __restrict__ in, f32x4* __restrict__ out) {
    const int lane = threadIdx.x & 63;
    const int sub  = lane & 31;            // element slot within half-wave
    const int f0   = (lane >> 5) * 8;      // frame base: 0 or 8
    const int wave = (blockIdx.x * blockDim.x + threadIdx.x) >> 6;
    const size_t e4 = (size_t)wave * 32 + sub;   // grid exactly covers M4

    f32x4 v[8];
    #pragma unroll
    for (int i = 0; i < 8; ++i) {
        v[i] = __builtin_nontemporal_load(&in[(size_t)(f0 + i) * M4 + e4]);
    }

    f32x4 s = v[0];
    #pragma unroll
    for (int i = 1; i < 8; ++i) s += v[i];

    // Half-wave join on the VALU: permlane32_swap(a,b) with a==b==s[c] gives
    //   a'[l<32]=s[l], a'[l>=32]=s[l-32]; b'[l<32]=s[l+32], b'[l>=32]=s[l]
    // so a' + b' = s[l] + s[l^32] in every lane.
    #pragma unroll
    for (int c = 0; c < 4; ++c) {
        unsigned u = __float_as_uint(s[c]);
        u32x2 r = __builtin_amdgcn_permlane32_swap(u, u, false, false);
        s[c] = __uint_as_float(r.x) + __uint_as_float(r.y);
    }

    #pragma unroll
    for (int i = 0; i < 8; ++i) {
        f32x4 o = v[i] * v[i] * s;
        out[(size_t)(f0 + i) * M4 + e4] = o;   // regular write-back store
    }
}

extern "C" void kernel_launch(void* const* d_in, const int* in_sizes, int n_in,
                              void* d_out, int out_size, void* d_ws, size_t ws_size,
                              hipStream_t stream) {
    const f32x4* in  = (const f32x4*)d_in[0];
    f32x4*       out = (f32x4*)d_out;

    const int threads = 256;
    // each wave covers 32 f32x4 elements; 4 waves/block -> 128 per block
    const int blocks  = M4 / 128;   // 8192, exact
    frame_similarly_kernel<<<blocks, threads, 0, stream>>>(in, out);
}

// Round 9
// 98.716 us; speedup vs baseline: 1.0329x; 1.0127x over previous
//
#include <hip/hip_runtime.h>

// frames: [N=16, B=4, C=64, H=128, W=128] fp32
// out[i] = frames[i]^2 * sum_j frames[j]
//
// FINAL (reverted to the R5 structure — best measured: 93.4 us, 5.75 TB/s,
// 91% of the 6.29 TB/s measured copy ceiling on MI355X):
//   - one f32x2 per thread (8 B/lane): 16 live frames = 32 data VGPRs ->
//     fits 8 waves/SIMD (max occupancy). f32x4 variants (64 data VGPRs or
//     half-wave frame-split dual-segment accesses) all measured slower.
//   - nontemporal LOADS: single-use input streams bypass L1/L2, don't evict
//     pending write lines.
//   - regular write-back STORES: writes batch in L2 and drain to HBM in
//     large bursts (nt stores measured -17%: fine-grained R/W turnarounds).
//   - full-wave contiguous 512B segment per memory instruction.

typedef float f32x2 __attribute__((ext_vector_type(2)));

constexpr int N_FRAMES = 16;
constexpr int M_ELEMS  = 4 * 64 * 128 * 128;   // 4,194,304 fp32 per frame
constexpr int M2       = M_ELEMS / 2;          // 2,097,152 f32x2 per frame

__global__ __launch_bounds__(256, 8) void frame_similarly_kernel(
    const f32x2* __restrict__ in, f32x2* __restrict__ out) {
    int e = blockIdx.x * blockDim.x + threadIdx.x;   // grid exactly covers M2

    f32x2 v[N_FRAMES];
    f32x2 s = (f32x2)(0.f, 0.f);

    #pragma unroll
    for (int i = 0; i < N_FRAMES; ++i) {
        v[i] = __builtin_nontemporal_load(&in[(size_t)i * M2 + e]);
    }
    #pragma unroll
    for (int i = 0; i < N_FRAMES; ++i) {
        s += v[i];
    }
    #pragma unroll
    for (int i = 0; i < N_FRAMES; ++i) {
        f32x2 o = v[i] * v[i] * s;
        out[(size_t)i * M2 + e] = o;   // regular write-back store
    }
}

extern "C" void kernel_launch(void* const* d_in, const int* in_sizes, int n_in,
                              void* d_out, int out_size, void* d_ws, size_t ws_size,
                              hipStream_t stream) {
    const f32x2* in  = (const f32x2*)d_in[0];
    f32x2*       out = (f32x2*)d_out;

    const int threads = 256;
    const int blocks  = M2 / threads;  // 8192, exact
    frame_similarly_kernel<<<blocks, threads, 0, stream>>>(in, out);
}